// Round 1
// baseline (1000.775 us; speedup 1.0000x reference)
//
#include <hip/hip_runtime.h>
#include <hip/hip_bf16.h>

// Problem constants
#define B_ 4
#define T_ 200
#define U_ 100
#define ENC_DIM 512
#define JDIM 640
#define VOCAB 1024
#define M_TOTAL (B_*T_*U_)   // 80000

typedef __attribute__((ext_vector_type(8))) short short8;
typedef __attribute__((ext_vector_type(4))) float float4v;
typedef __attribute__((ext_vector_type(4))) unsigned short ushort4v;

__device__ __forceinline__ unsigned short f2bf(float x) {
    unsigned u = __builtin_bit_cast(unsigned, x);
    u += 0x7fffu + ((u >> 16) & 1u);   // round-to-nearest-even
    return (unsigned short)(u >> 16);
}

__device__ __forceinline__ float fast_tanh(float x) {
    // tanh(x) = 1 - 2/(exp(2x)+1); saturates correctly for large |x|
    return 1.0f - 2.0f / (__expf(2.0f * x) + 1.0f);
}

// ---------------------------------------------------------------------------
// Projection: Y[R,640] = X[R,512] @ W[512,640] (+ bias). 8 rows per block.
// ---------------------------------------------------------------------------
__global__ __launch_bounds__(256)
void proj_kernel(const float* __restrict__ X, const float* __restrict__ W,
                 const float* __restrict__ bias, float* __restrict__ Y) {
    __shared__ float lds[8 * ENC_DIM];   // 16 KB
    const int tid = threadIdx.x;
    const int row0 = blockIdx.x * 8;

    #pragma unroll
    for (int i = 0; i < 16; ++i) {       // 8*512 = 4096 floats, 16/thread
        int idx = i * 256 + tid;
        lds[idx] = X[row0 * ENC_DIM + idx];
    }
    __syncthreads();

    for (int j = tid; j < JDIM; j += 256) {
        float acc[8];
        #pragma unroll
        for (int r = 0; r < 8; ++r) acc[r] = 0.f;
        for (int k = 0; k < ENC_DIM; ++k) {
            float w = W[k * JDIM + j];
            #pragma unroll
            for (int r = 0; r < 8; ++r) acc[r] += lds[r * ENC_DIM + k] * w;
        }
        float bb = bias ? bias[j] : 0.f;
        #pragma unroll
        for (int r = 0; r < 8; ++r) Y[(row0 + r) * JDIM + j] = acc[r] + bb;
    }
}

// ---------------------------------------------------------------------------
// Transpose + cast: Wt[n][k] = bf16(W_out[k][n]).  W_out: [640,1024]
// ---------------------------------------------------------------------------
__global__ __launch_bounds__(256)
void transpose_cast(const float* __restrict__ W, unsigned short* __restrict__ Wt) {
    __shared__ float tile[32][33];
    const int bk = blockIdx.x;   // 0..19  (k tiles)
    const int bn = blockIdx.y;   // 0..31  (n tiles)
    const int tx = threadIdx.x;  // 0..31
    const int ty = threadIdx.y;  // 0..7
    #pragma unroll
    for (int i = 0; i < 32; i += 8)
        tile[ty + i][tx] = W[(bk * 32 + ty + i) * VOCAB + bn * 32 + tx];
    __syncthreads();
    #pragma unroll
    for (int i = 0; i < 32; i += 8)
        Wt[(bn * 32 + ty + i) * JDIM + bk * 32 + tx] = f2bf(tile[tx][ty + i]);
}

// ---------------------------------------------------------------------------
// Fused joint GEMM: out[m, v] = tanh(enc[row(m)] + pred[row(m)])· Wt^T + b_out
// M=80000, K=640, N=1024.  BM=BN=128, BK=64, 256 threads = 4 waves (2x2 of 64x64)
// ---------------------------------------------------------------------------
#define BM 128
#define BN 128
#define BK 64
#define LDST 72   // padded LDS stride (bf16 elems); 144B = 9*16B, b128-aligned

__global__ __launch_bounds__(256, 2)
void joint_gemm(const float* __restrict__ encp,   // [800, 640]
                const float* __restrict__ predp,  // [400, 640]
                const unsigned short* __restrict__ Wt,  // [1024, 640] bf16
                const float* __restrict__ bout,   // [1024]
                float* __restrict__ out)          // [80000, 1024]
{
    __shared__ __align__(16) unsigned short As[BM * LDST];
    __shared__ __align__(16) unsigned short Bs[BN * LDST];

    const int tid = threadIdx.x;
    const int bm = blockIdx.x;   // 0..624
    const int bn = blockIdx.y;   // 0..7

    // ---- A staging indices: thread covers rows i*16 + (tid>>4), k chunk (tid&15)*4
    const int rbase = tid >> 4;          // 0..15
    const int c4 = (tid & 15) * 4;       // 0,4,...,60
    int encOff[8], predOff[8];
    #pragma unroll
    for (int i = 0; i < 8; ++i) {
        int mg  = bm * BM + i * 16 + rbase;
        int b   = mg / (T_ * U_);
        int rem = mg - b * (T_ * U_);
        int t   = rem / U_;
        int u   = rem - t * U_;
        encOff[i]  = (b * T_ + t) * JDIM + c4;
        predOff[i] = (b * U_ + u) * JDIM + c4;
    }
    // ---- B staging indices: thread covers rows i*32 + (tid>>3), k chunk (tid&7)*8
    const int nrow = tid >> 3;           // 0..31
    const int bk8  = (tid & 7) * 8;      // 0,8,...,56
    const long wtBase = (long)(bn * BN) * JDIM;

    // ---- wave/fragment coordinates
    const int wave = tid >> 6;
    const int lane = tid & 63;
    const int wm   = (wave >> 1) * 64;
    const int wn   = (wave & 1) * 64;
    const int lm   = lane & 15;
    const int quad = lane >> 4;

    float4v acc[4][4];
    #pragma unroll
    for (int i = 0; i < 4; ++i)
        #pragma unroll
        for (int j = 0; j < 4; ++j)
            acc[i][j] = (float4v){0.f, 0.f, 0.f, 0.f};

    for (int k0 = 0; k0 < JDIM; k0 += BK) {
        // stage A: compute tanh(enc+pred) -> bf16 -> LDS
        #pragma unroll
        for (int i = 0; i < 8; ++i) {
            int row = i * 16 + rbase;
            float4v e4 = *(const float4v*)(encp + encOff[i] + k0);
            float4v p4 = *(const float4v*)(predp + predOff[i] + k0);
            ushort4v v;
            v.x = f2bf(fast_tanh(e4.x + p4.x));
            v.y = f2bf(fast_tanh(e4.y + p4.y));
            v.z = f2bf(fast_tanh(e4.z + p4.z));
            v.w = f2bf(fast_tanh(e4.w + p4.w));
            *(ushort4v*)(&As[row * LDST + c4]) = v;
        }
        // stage B (already bf16, k-contiguous): 16B copies
        #pragma unroll
        for (int i = 0; i < 4; ++i) {
            int n = i * 32 + nrow;
            float4v w = *(const float4v*)((const float*)(Wt + wtBase + (long)n * JDIM + k0 + bk8));
            *(float4v*)(&Bs[n * LDST + bk8]) = w;
        }
        __syncthreads();

        #pragma unroll
        for (int kk = 0; kk < BK; kk += 32) {
            short8 a[4], b[4];
            #pragma unroll
            for (int i = 0; i < 4; ++i)
                a[i] = *(const short8*)(&As[(wm + i * 16 + lm) * LDST + kk + quad * 8]);
            #pragma unroll
            for (int j = 0; j < 4; ++j)
                b[j] = *(const short8*)(&Bs[(wn + j * 16 + lm) * LDST + kk + quad * 8]);
            #pragma unroll
            for (int i = 0; i < 4; ++i)
                #pragma unroll
                for (int j = 0; j < 4; ++j)
                    acc[i][j] = __builtin_amdgcn_mfma_f32_16x16x32_bf16(a[i], b[j], acc[i][j], 0, 0, 0);
        }
        __syncthreads();
    }

    // epilogue: C/D layout col=lane&15, row=quad*4+r
    #pragma unroll
    for (int j = 0; j < 4; ++j) {
        int ng = bn * BN + wn + j * 16 + lm;
        float bias = bout[ng];
        #pragma unroll
        for (int i = 0; i < 4; ++i) {
            int mg0 = bm * BM + wm + i * 16 + quad * 4;
            #pragma unroll
            for (int r = 0; r < 4; ++r)
                out[(long)(mg0 + r) * VOCAB + ng] = acc[i][j][r] + bias;
        }
    }
}

// ---------------------------------------------------------------------------
extern "C" void kernel_launch(void* const* d_in, const int* in_sizes, int n_in,
                              void* d_out, int out_size, void* d_ws, size_t ws_size,
                              hipStream_t stream) {
    const float* enc_out  = (const float*)d_in[0];  // [4,200,512]
    const float* pred_out = (const float*)d_in[1];  // [4,100,512]
    const float* W_enc    = (const float*)d_in[2];  // [512,640]
    const float* b_enc    = (const float*)d_in[3];  // [640]
    const float* W_pred   = (const float*)d_in[4];  // [512,640]
    const float* W_out    = (const float*)d_in[5];  // [640,1024]
    const float* b_out    = (const float*)d_in[6];  // [1024]
    float* out = (float*)d_out;

    // workspace layout (16B aligned throughout)
    float* encp  = (float*)d_ws;                       // 800*640 fp32 = 2.048 MB
    float* predp = encp + 800 * JDIM;                  // 400*640 fp32 = 1.024 MB
    unsigned short* Wt = (unsigned short*)(predp + 400 * JDIM); // 1024*640 bf16 = 1.31 MB

    proj_kernel<<<100, 256, 0, stream>>>(enc_out, W_enc, b_enc, encp);
    proj_kernel<<<50, 256, 0, stream>>>(pred_out, W_pred, nullptr, predp);
    transpose_cast<<<dim3(20, 32), dim3(32, 8), 0, stream>>>(W_out, Wt);
    joint_gemm<<<dim3(625, 8), 256, 0, stream>>>(encp, predp, Wt, b_out, out);
}

// Round 2
// 555.480 us; speedup vs baseline: 1.8016x; 1.8016x over previous
//
#include <hip/hip_runtime.h>
#include <hip/hip_bf16.h>

// Problem constants
#define B_ 4
#define T_ 200
#define U_ 100
#define ENC_DIM 512
#define JDIM 640
#define VOCAB 1024
#define M_TOTAL (B_*T_*U_)   // 80000

typedef __attribute__((ext_vector_type(8))) short short8;
typedef __attribute__((ext_vector_type(4))) float float4v;
typedef __attribute__((ext_vector_type(4))) unsigned short ushort4v;

__device__ __forceinline__ unsigned short f2bf(float x) {
    unsigned u = __builtin_bit_cast(unsigned, x);
    u += 0x7fffu + ((u >> 16) & 1u);   // round-to-nearest-even
    return (unsigned short)(u >> 16);
}

__device__ __forceinline__ float fast_tanh(float x) {
    return 1.0f - 2.0f / (__expf(2.0f * x) + 1.0f);
}

__device__ __forceinline__ void gload_lds16(const void* g, void* l) {
    __builtin_amdgcn_global_load_lds(
        (const __attribute__((address_space(1))) unsigned int*)g,
        (__attribute__((address_space(3))) unsigned int*)l, 16, 0, 0);
}

// ---------------------------------------------------------------------------
// Projection: Y[M,640] = X[M,512] @ W[512,640] (+ bias). 32x64 tiles, fp32.
// ---------------------------------------------------------------------------
#define PBM 32
#define PBN 64
#define PBK 32

__global__ __launch_bounds__(256)
void proj_tiled(const float* __restrict__ X, const float* __restrict__ W,
                const float* __restrict__ bias, float* __restrict__ Y, int M) {
    __shared__ float Xs[PBM][36];
    __shared__ float Ws[PBK][68];
    const int tid = threadIdx.x;
    const int row0 = blockIdx.x * PBM;
    const int col0 = blockIdx.y * PBN;

    const int xr = tid >> 3;          // 0..31 (X stage row)
    const int xk = (tid & 7) * 4;     // X stage k chunk
    const int wk = tid >> 4;          // 0..15 (W stage k)
    const int wn = (tid & 15) * 4;    // W stage n chunk

    const int ty = tid >> 4;          // 0..15 output row (and +16)
    const int tx = tid & 15;          // output col group (x4)

    int xrow = row0 + xr; if (xrow >= M) xrow = M - 1;

    float4v acc0 = {0.f,0.f,0.f,0.f}, acc1 = {0.f,0.f,0.f,0.f};

    for (int k0 = 0; k0 < ENC_DIM; k0 += PBK) {
        *(float4v*)&Xs[xr][xk] = *(const float4v*)(X + (size_t)xrow * ENC_DIM + k0 + xk);
        #pragma unroll
        for (int i = 0; i < 2; ++i)
            *(float4v*)&Ws[wk + i*16][wn] =
                *(const float4v*)(W + (size_t)(k0 + wk + i*16) * JDIM + col0 + wn);
        __syncthreads();
        #pragma unroll
        for (int k = 0; k < PBK; ++k) {
            float a0 = Xs[ty][k];
            float a1 = Xs[ty + 16][k];
            float4v w = *(const float4v*)&Ws[k][tx * 4];
            acc0 += w * a0;
            acc1 += w * a1;
        }
        __syncthreads();
    }

    float4v bb = {0.f,0.f,0.f,0.f};
    if (bias) bb = *(const float4v*)(bias + col0 + tx * 4);
    int r0 = row0 + ty, r1 = row0 + ty + 16;
    if (r0 < M) *(float4v*)(Y + (size_t)r0 * JDIM + col0 + tx*4) = acc0 + bb;
    if (r1 < M) *(float4v*)(Y + (size_t)r1 * JDIM + col0 + tx*4) = acc1 + bb;
}

// ---------------------------------------------------------------------------
// Transpose + cast: Wt[n][k] = bf16(W_out[k][n]).  W_out: [640,1024]
// ---------------------------------------------------------------------------
__global__ __launch_bounds__(256)
void transpose_cast(const float* __restrict__ W, unsigned short* __restrict__ Wt) {
    __shared__ float tile[32][33];
    const int bk = blockIdx.x;   // 0..19
    const int bn = blockIdx.y;   // 0..31
    const int tx = threadIdx.x;  // 0..31
    const int ty = threadIdx.y;  // 0..7
    #pragma unroll
    for (int i = 0; i < 32; i += 8)
        tile[ty + i][tx] = W[(bk * 32 + ty + i) * VOCAB + bn * 32 + tx];
    __syncthreads();
    #pragma unroll
    for (int i = 0; i < 32; i += 8)
        Wt[(bn * 32 + ty + i) * JDIM + bk * 32 + tx] = f2bf(tile[tx][ty + i]);
}

// ---------------------------------------------------------------------------
// joint_tanh: jbuf[m-m0][k] = bf16(tanh(encp[row(m)][k] + predp[row(m)][k]))
// 4 elems/thread, fully coalesced.
// ---------------------------------------------------------------------------
__global__ __launch_bounds__(256)
void joint_tanh(const float* __restrict__ encp, const float* __restrict__ predp,
                unsigned short* __restrict__ jbuf, int m0, int mcount) {
    int idx = blockIdx.x * 256 + threadIdx.x;
    if (idx >= mcount * (JDIM / 4)) return;
    int m  = idx / (JDIM / 4);
    int c4 = (idx - m * (JDIM / 4)) * 4;
    int mg = m0 + m;
    int b   = mg / (T_ * U_);
    int rem = mg - b * (T_ * U_);
    int t   = rem / U_;
    int u   = rem - t * U_;
    float4v e = *(const float4v*)(encp  + (size_t)(b * T_ + t) * JDIM + c4);
    float4v p = *(const float4v*)(predp + (size_t)(b * U_ + u) * JDIM + c4);
    ushort4v v;
    v.x = f2bf(fast_tanh(e.x + p.x));
    v.y = f2bf(fast_tanh(e.y + p.y));
    v.z = f2bf(fast_tanh(e.z + p.z));
    v.w = f2bf(fast_tanh(e.w + p.w));
    *(ushort4v*)(jbuf + (size_t)m * JDIM + c4) = v;
}

// ---------------------------------------------------------------------------
// Pure bf16 GEMM, m97 structure: out = A @ Wt^T + b_out
// A: [mc,640] bf16 k-contig.  Wt: [1024,640] bf16 k-contig.
// BM=BN=128, BK=64, 256 thr (2x2 waves, 4x4 frags), global_load_lds w=16.
// ---------------------------------------------------------------------------
#define GBM 128
#define GBN 128
#define GBK 64

__global__ __launch_bounds__(256, 2)
void gemm_joint(const unsigned short* __restrict__ A,
                const unsigned short* __restrict__ Wt,
                const float* __restrict__ bout,
                float* __restrict__ out)
{
    __shared__ __align__(16) unsigned short As[GBM * GBK];  // 16 KB
    __shared__ __align__(16) unsigned short Bs[GBN * GBK];  // 16 KB

    const int tid = threadIdx.x;
    const int bm = blockIdx.x;
    const int bn = blockIdx.y;

    // staging: thread covers row (tid>>3)+32i, k-chunk (tid&7)*8; LDS dst = tid*16B + i*4KB
    const int srow = tid >> 3;
    const int scol = (tid & 7) * 8;
    const unsigned short* aBase = A  + (size_t)(bm * GBM + srow) * JDIM + scol;
    const unsigned short* bBase = Wt + (size_t)(bn * GBN + srow) * JDIM + scol;
    unsigned short* asDst = &As[srow * GBK + scol];
    unsigned short* bsDst = &Bs[srow * GBK + scol];

    const int wave = tid >> 6, lane = tid & 63;
    const int wm = (wave >> 1) * 64, wn = (wave & 1) * 64;
    const int lm = lane & 15, quad = lane >> 4;

    float4v acc[4][4];
    #pragma unroll
    for (int i = 0; i < 4; ++i)
        #pragma unroll
        for (int j = 0; j < 4; ++j)
            acc[i][j] = (float4v){0.f, 0.f, 0.f, 0.f};

    for (int k0 = 0; k0 < JDIM; k0 += GBK) {
        #pragma unroll
        for (int i = 0; i < 4; ++i) {
            gload_lds16(aBase + (size_t)i * 32 * JDIM + k0, asDst + i * 32 * GBK);
            gload_lds16(bBase + (size_t)i * 32 * JDIM + k0, bsDst + i * 32 * GBK);
        }
        __syncthreads();

        #pragma unroll
        for (int kk = 0; kk < GBK; kk += 32) {
            short8 a[4], b[4];
            #pragma unroll
            for (int i = 0; i < 4; ++i)
                a[i] = *(const short8*)(&As[(wm + i * 16 + lm) * GBK + kk + quad * 8]);
            #pragma unroll
            for (int j = 0; j < 4; ++j)
                b[j] = *(const short8*)(&Bs[(wn + j * 16 + lm) * GBK + kk + quad * 8]);
            #pragma unroll
            for (int i = 0; i < 4; ++i)
                #pragma unroll
                for (int j = 0; j < 4; ++j)
                    acc[i][j] = __builtin_amdgcn_mfma_f32_16x16x32_bf16(a[i], b[j], acc[i][j], 0, 0, 0);
        }
        __syncthreads();
    }

    #pragma unroll
    for (int j = 0; j < 4; ++j) {
        int ng = bn * GBN + wn + j * 16 + lm;
        float bias = bout[ng];
        #pragma unroll
        for (int i = 0; i < 4; ++i) {
            int mg0 = bm * GBM + wm + i * 16 + quad * 4;
            #pragma unroll
            for (int r = 0; r < 4; ++r)
                out[(size_t)(mg0 + r) * VOCAB + ng] = acc[i][j][r] + bias;
        }
    }
}

// ---------------------------------------------------------------------------
// Fallback (ws too small): round-1 fused kernel — tanh recomputed per N-tile.
// ---------------------------------------------------------------------------
#define BM 128
#define BN 128
#define BK 64
#define LDST 72

__global__ __launch_bounds__(256, 2)
void joint_gemm_fused(const float* __restrict__ encp, const float* __restrict__ predp,
                      const unsigned short* __restrict__ Wt, const float* __restrict__ bout,
                      float* __restrict__ out)
{
    __shared__ __align__(16) unsigned short As[BM * LDST];
    __shared__ __align__(16) unsigned short Bs[BN * LDST];
    const int tid = threadIdx.x;
    const int bm = blockIdx.x, bn = blockIdx.y;
    const int rbase = tid >> 4;
    const int c4 = (tid & 15) * 4;
    int encOff[8], predOff[8];
    #pragma unroll
    for (int i = 0; i < 8; ++i) {
        int mg  = bm * BM + i * 16 + rbase;
        int b   = mg / (T_ * U_);
        int rem = mg - b * (T_ * U_);
        int t   = rem / U_;
        int u   = rem - t * U_;
        encOff[i]  = (b * T_ + t) * JDIM + c4;
        predOff[i] = (b * U_ + u) * JDIM + c4;
    }
    const int nrow = tid >> 3;
    const int bk8  = (tid & 7) * 8;
    const size_t wtBase = (size_t)(bn * BN) * JDIM;
    const int wave = tid >> 6, lane = tid & 63;
    const int wm = (wave >> 1) * 64, wn = (wave & 1) * 64;
    const int lm = lane & 15, quad = lane >> 4;

    float4v acc[4][4];
    #pragma unroll
    for (int i = 0; i < 4; ++i)
        #pragma unroll
        for (int j = 0; j < 4; ++j)
            acc[i][j] = (float4v){0.f, 0.f, 0.f, 0.f};

    for (int k0 = 0; k0 < JDIM; k0 += BK) {
        #pragma unroll
        for (int i = 0; i < 8; ++i) {
            int row = i * 16 + rbase;
            float4v e4 = *(const float4v*)(encp + encOff[i] + k0);
            float4v p4 = *(const float4v*)(predp + predOff[i] + k0);
            ushort4v v;
            v.x = f2bf(fast_tanh(e4.x + p4.x));
            v.y = f2bf(fast_tanh(e4.y + p4.y));
            v.z = f2bf(fast_tanh(e4.z + p4.z));
            v.w = f2bf(fast_tanh(e4.w + p4.w));
            *(ushort4v*)(&As[row * LDST + c4]) = v;
        }
        #pragma unroll
        for (int i = 0; i < 4; ++i) {
            int n = i * 32 + nrow;
            float4v w = *(const float4v*)((const float*)(Wt + wtBase + (size_t)n * JDIM + k0 + bk8));
            *(float4v*)(&Bs[n * LDST + bk8]) = w;
        }
        __syncthreads();
        #pragma unroll
        for (int kk = 0; kk < BK; kk += 32) {
            short8 a[4], b[4];
            #pragma unroll
            for (int i = 0; i < 4; ++i)
                a[i] = *(const short8*)(&As[(wm + i * 16 + lm) * LDST + kk + quad * 8]);
            #pragma unroll
            for (int j = 0; j < 4; ++j)
                b[j] = *(const short8*)(&Bs[(wn + j * 16 + lm) * LDST + kk + quad * 8]);
            #pragma unroll
            for (int i = 0; i < 4; ++i)
                #pragma unroll
                for (int j = 0; j < 4; ++j)
                    acc[i][j] = __builtin_amdgcn_mfma_f32_16x16x32_bf16(a[i], b[j], acc[i][j], 0, 0, 0);
        }
        __syncthreads();
    }
    #pragma unroll
    for (int j = 0; j < 4; ++j) {
        int ng = bn * BN + wn + j * 16 + lm;
        float bias = bout[ng];
        #pragma unroll
        for (int i = 0; i < 4; ++i) {
            int mg0 = bm * BM + wm + i * 16 + quad * 4;
            #pragma unroll
            for (int r = 0; r < 4; ++r)
                out[(size_t)(mg0 + r) * VOCAB + ng] = acc[i][j][r] + bias;
        }
    }
}

// ---------------------------------------------------------------------------
extern "C" void kernel_launch(void* const* d_in, const int* in_sizes, int n_in,
                              void* d_out, int out_size, void* d_ws, size_t ws_size,
                              hipStream_t stream) {
    const float* enc_out  = (const float*)d_in[0];  // [4,200,512]
    const float* pred_out = (const float*)d_in[1];  // [4,100,512]
    const float* W_enc    = (const float*)d_in[2];  // [512,640]
    const float* b_enc    = (const float*)d_in[3];  // [640]
    const float* W_pred   = (const float*)d_in[4];  // [512,640]
    const float* W_out    = (const float*)d_in[5];  // [640,1024]
    const float* b_out    = (const float*)d_in[6];  // [1024]
    float* out = (float*)d_out;

    float* encp  = (float*)d_ws;                                 // 800*640 fp32
    float* predp = encp + 800 * JDIM;                            // 400*640 fp32
    unsigned short* Wt = (unsigned short*)(predp + 400 * JDIM);  // 1024*640 bf16
    unsigned short* jbuf = Wt + (size_t)VOCAB * JDIM;            // chunked joint bf16

    const size_t fixedBytes = (800 * JDIM + 400 * JDIM) * sizeof(float)
                            + (size_t)VOCAB * JDIM * sizeof(unsigned short);

    proj_tiled<<<dim3(25, 10), 256, 0, stream>>>(enc_out, W_enc, b_enc, encp, 800);
    proj_tiled<<<dim3(13, 10), 256, 0, stream>>>(pred_out, W_pred, nullptr, predp, 400);
    transpose_cast<<<dim3(20, 32), dim3(32, 8), 0, stream>>>(W_out, Wt);

    size_t avail = ws_size > fixedBytes ? ws_size - fixedBytes : 0;
    long mcMax = (long)(avail / (JDIM * sizeof(unsigned short)));
    mcMax = (mcMax / 128) * 128;
    if (mcMax > M_TOTAL) mcMax = M_TOTAL;

    if (mcMax >= 8192) {
        for (int m0 = 0; m0 < M_TOTAL; m0 += (int)mcMax) {
            int mc = M_TOTAL - m0 < mcMax ? M_TOTAL - m0 : (int)mcMax;  // always mult of 128
            int nThreadsChunks = mc * (JDIM / 4);
            joint_tanh<<<(nThreadsChunks + 255) / 256, 256, 0, stream>>>(encp, predp, jbuf, m0, mc);
            gemm_joint<<<dim3(mc / GBM, VOCAB / GBN), 256, 0, stream>>>(jbuf, Wt, b_out,
                                                                        out + (size_t)m0 * VOCAB);
        }
    } else {
        // scratch too small for materialization — round-1 fused path
        joint_gemm_fused<<<dim3(M_TOTAL / BM, VOCAB / BN), 256, 0, stream>>>(encp, predp, Wt, b_out, out);
    }
}